// Round 10
// baseline (299.083 us; speedup 1.0000x reference)
//
#include <hip/hip_runtime.h>
#include <stdint.h>

#define TS 2048
#define DM 2048
#define NH 16
#define DH 128

typedef unsigned short u16t;
typedef __attribute__((ext_vector_type(8))) short short8;
typedef __attribute__((ext_vector_type(4))) float f32x4;
typedef __attribute__((ext_vector_type(4))) unsigned int u32x4;
typedef __attribute__((ext_vector_type(4))) unsigned short u16x4;

__device__ __forceinline__ float bf2f(u16t b) {
  return __uint_as_float(((unsigned int)b) << 16);
}
__device__ __forceinline__ u16t f2bf(float f) {
  unsigned int u = __float_as_uint(f);
  u += 0x7FFFu + ((u >> 16) & 1u);   // round-to-nearest-even
  return (u16t)(u >> 16);
}

// async global->LDS, 16B per lane. LDS dest = wave-uniform base + lane*16.
__device__ __forceinline__ void async_copy16(const u16t* g, u16t* l) {
  __builtin_amdgcn_global_load_lds((const __attribute__((address_space(1))) void*)g,
                                   (__attribute__((address_space(3))) void*)l, 16, 0, 0);
}

// DPP row_ror within 16-lane rows: pure-VALU cross-lane (vs ds_bpermute for __shfl).
#define DPP_ROR_F(x, n) __uint_as_float(__builtin_amdgcn_update_dpp( \
    0, (int)__float_as_uint(x), 0x120 | (n), 0xF, 0xF, true))

__device__ __forceinline__ float row16_max(float x) {
  x = fmaxf(x, DPP_ROR_F(x, 8));
  x = fmaxf(x, DPP_ROR_F(x, 4));
  x = fmaxf(x, DPP_ROR_F(x, 2));
  x = fmaxf(x, DPP_ROR_F(x, 1));
  return x;
}
__device__ __forceinline__ float row16_sum(float x) {
  x += DPP_ROR_F(x, 8);
  x += DPP_ROR_F(x, 4);
  x += DPP_ROR_F(x, 2);
  x += DPP_ROR_F(x, 1);
  return x;
}

// ---------------- fused: fp32->bf16 weight cast (blocks 0..16383) + RMSNorm (rest) ----
// Wq/Wk rows are PERMUTED within each head at cast time so that RoPE partners
// (d, d+64) land at columns (p, p+16): p = (d>>4)*32 + (d&15) [+16 for d>=64].
// In the GEMM C-fragment, col and col+16 are the same lane / adjacent nt register,
// so RoPE becomes a pure in-register epilogue op. Q.K dot is invariant (same perm).
__global__ __launch_bounds__(256) void cast_rms_kernel(const float* __restrict__ W0,
                                                       const float* __restrict__ W1,
                                                       const float* __restrict__ W2,
                                                       const float* __restrict__ W3,
                                                       u16t* __restrict__ outw,
                                                       const float* __restrict__ x,
                                                       const float* __restrict__ lnw,
                                                       u16t* __restrict__ h) {
  if (blockIdx.x < 16384) {
    const int idx = blockIdx.x * 256 + threadIdx.x;   // 4M threads, 4 elems each
    const int mat = idx >> 20;
    const size_t off = (size_t)(idx & 0xFFFFF) * 4;
    const float* W = (mat == 0) ? W0 : (mat == 1) ? W1 : (mat == 2) ? W2 : W3;
    const f32x4 v = *(const f32x4*)(W + off);
    size_t dstoff = off;
    if (mat < 2) {   // permute output-feature rows of Wq, Wk
      const int row = (int)(off >> 11);
      const int col = (int)(off & 2047);
      const int d = row & 127;
      const int e = d & 63;
      const int p = ((e >> 4) * 32 + (e & 15)) + ((d >> 6) << 4);
      dstoff = ((size_t)((row & ~127) | p) << 11) | (size_t)col;
    }
    union { u16t s[4]; uint64_t u; } o;
#pragma unroll
    for (int i = 0; i < 4; ++i) o.s[i] = f2bf(v[i]);
    *(uint64_t*)(outw + (size_t)mat * (DM * DM) + dstoff) = o.u;
    return;
  }
  const int row = blockIdx.x - 16384;
  const int tid = threadIdx.x;
  const float* xr = x + (size_t)row * DM + tid * 8;
  f32x4 v0 = *(const f32x4*)(xr);
  f32x4 v1 = *(const f32x4*)(xr + 4);
  float f[8];
#pragma unroll
  for (int i = 0; i < 4; ++i) { f[i] = v0[i]; f[i + 4] = v1[i]; }
  float ss = 0.f;
#pragma unroll
  for (int i = 0; i < 8; ++i) ss += f[i] * f[i];
#pragma unroll
  for (int off = 1; off < 64; off <<= 1) ss += __shfl_xor(ss, off, 64);
  __shared__ float wsum[4];
  if ((tid & 63) == 0) wsum[tid >> 6] = ss;
  __syncthreads();
  float tot = wsum[0] + wsum[1] + wsum[2] + wsum[3];
  float rs = rsqrtf(tot * (1.0f / DM) + 1e-5f);
  f32x4 w0 = *(const f32x4*)(lnw + tid * 8);
  f32x4 w1 = *(const f32x4*)(lnw + tid * 8 + 4);
  u32x4 o;
#pragma unroll
  for (int i = 0; i < 4; ++i) {
    unsigned int lo = f2bf(f[2 * i]     * ((2 * i     < 4) ? w0[2 * i]     : w1[2 * i - 4]) * rs);
    unsigned int hi = f2bf(f[2 * i + 1] * ((2 * i + 1 < 4) ? w0[2 * i + 1] : w1[2 * i - 3]) * rs);
    o[i] = lo | (hi << 16);
  }
  *(u32x4*)(h + (size_t)row * DM + tid * 8) = o;
}

// ---------------- fused QKV GEMM: one block computes Q,K,V for a 128x128 tile ----------
// (verified round 9: 78.6 us, 655 TF, conflicts 0 — frozen this round as control)
__global__ __launch_bounds__(512, 2) void gemm_qkv(
    const u16t* __restrict__ A,
    const u16t* __restrict__ B0, const u16t* __restrict__ B1, const u16t* __restrict__ B2,
    u16t* __restrict__ Cq, u16t* __restrict__ Ck, u16t* __restrict__ Cv,
    const float* __restrict__ cosb, const float* __restrict__ sinb) {
  __shared__ u16t Ab[2][128 * 64];      // 32 KB
  __shared__ u16t Bb[3][2][128 * 64];   // 96 KB
  const int tid  = threadIdx.x;
  const int wave = tid >> 6;
  const int lane = tid & 63;
  const int quad = lane >> 4;
  const int c16  = lane & 15;
  const int h7   = c16 & 7;
  const int wm   = wave >> 2;        // 0..1  (token half: 64 rows)
  const int wn   = wave & 3;         // 0..3  (feature quarter: 32 cols)
  const int bid  = blockIdx.x;
  const int wgid = (bid & 7) * 32 + (bid >> 3);
  const int m0   = (wgid & 15) * 128;
  const int n0   = (wgid >> 4) * 128;

  const int srow = lane >> 3;               // 0..7
  const int sg   = (lane & 7) ^ srow;       // permuted 16B granule
  auto stage = [&](int d, int k0) {
    const size_t koff = (size_t)k0 + sg * 8;
#pragma unroll
    for (int c = 0; c < 2; ++c) {
      const int rb = wave * 16 + c * 8;     // chunk row base 0..127 (multiple of 8)
      async_copy16(A  + (size_t)(m0 + rb + srow) * DM + koff, &Ab[d][rb * 64]);
      async_copy16(B0 + (size_t)(n0 + rb + srow) * DM + koff, &Bb[0][d][rb * 64]);
      async_copy16(B1 + (size_t)(n0 + rb + srow) * DM + koff, &Bb[1][d][rb * 64]);
      async_copy16(B2 + (size_t)(n0 + rb + srow) * DM + koff, &Bb[2][d][rb * 64]);
    }
  };

  const f32x4 fzero = {0.f, 0.f, 0.f, 0.f};
  f32x4 acc[3][4][2];   // [mat][mt][nt] -> 96 VGPR
#pragma unroll
  for (int m = 0; m < 3; ++m)
#pragma unroll
    for (int i = 0; i < 4; ++i)
#pragma unroll
      for (int j = 0; j < 2; ++j) acc[m][i][j] = fzero;

  stage(0, 0);
  asm volatile("s_waitcnt vmcnt(0)" ::: "memory");
  __builtin_amdgcn_s_barrier();

  for (int kt = 0; kt < DM / 64; ++kt) {
    const int cur = kt & 1;
    if (kt + 1 < DM / 64) stage(cur ^ 1, (kt + 1) * 64);   // prefetch under compute
    const u16t* Abuf = Ab[cur];
    __builtin_amdgcn_s_setprio(1);
#pragma unroll
    for (int ks = 0; ks < 2; ++ks) {       // two K=32 halves
      const int gsw = ((ks * 4 + quad) ^ h7) * 8;
      short8 af[4], bfr[3][2];
#pragma unroll
      for (int i = 0; i < 4; ++i)
        af[i] = *(const short8*)(Abuf + (wm * 64 + i * 16 + c16) * 64 + gsw);
#pragma unroll
      for (int m = 0; m < 3; ++m)
#pragma unroll
        for (int nt = 0; nt < 2; ++nt)
          bfr[m][nt] = *(const short8*)(&Bb[m][cur][0] + (wn * 32 + nt * 16 + c16) * 64 + gsw);
#pragma unroll
      for (int m = 0; m < 3; ++m)
#pragma unroll
        for (int i = 0; i < 4; ++i)
#pragma unroll
          for (int nt = 0; nt < 2; ++nt)
            acc[m][i][nt] =
                __builtin_amdgcn_mfma_f32_16x16x32_bf16(af[i], bfr[m][nt], acc[m][i][nt], 0, 0, 0);
    }
    __builtin_amdgcn_s_setprio(0);
    asm volatile("s_waitcnt vmcnt(0)" ::: "memory");
    __builtin_amdgcn_s_barrier();
  }

  // Q/K with fused RoPE: each wave's cols are (p, p+16) pairs, p = wn*32 + c16.
#pragma unroll
  for (int mat = 0; mat < 2; ++mat) {
    u16t* C = mat ? Ck : Cq;
#pragma unroll
    for (int mt = 0; mt < 4; ++mt) {
#pragma unroll
      for (int r = 0; r < 4; ++r) {
        const int row = m0 + wm * 64 + mt * 16 + quad * 4 + r;   // = token t
        const size_t base = (size_t)row * DM;
        const int col = n0 + wn * 32 + c16;
        const int p = col & 127;
        const int dorig = ((p >> 5) << 4) + c16;
        const float cv = cosb[row * DH + dorig];
        const float sv = sinb[row * DH + dorig];
        const float x1 = acc[mat][mt][0][r];
        const float x2 = acc[mat][mt][1][r];
        C[base + col]      = f2bf(x1 * cv - x2 * sv);
        C[base + col + 16] = f2bf(x2 * cv + x1 * sv);
      }
    }
  }
  // V: transposed store
#pragma unroll
  for (int mt = 0; mt < 4; ++mt) {
#pragma unroll
    for (int r = 0; r < 4; ++r) {
      const int row = m0 + wm * 64 + mt * 16 + quad * 4 + r;
#pragma unroll
      for (int nt = 0; nt < 2; ++nt) {
        const int col = n0 + wn * 32 + nt * 16 + c16;
        Cv[(size_t)col * TS + row] = f2bf(acc[2][mt][nt][r]);
      }
    }
  }
}

// ---------------- out-proj GEMM: 256x256 tile, split-K=4, 2-phase (frozen) ----
__global__ __launch_bounds__(512, 2) void gemm_out(
    const u16t* __restrict__ A, const u16t* __restrict__ B0,
    u16t* __restrict__ P0, u16t* __restrict__ P1,
    u16t* __restrict__ P2, u16t* __restrict__ P3) {
  __shared__ u16t Ab[2][256 * 64];   // 64 KB
  __shared__ u16t Bb[2][256 * 64];   // 64 KB
  const int tid  = threadIdx.x;
  const int wave = tid >> 6;
  const int lane = tid & 63;
  const int quad = lane >> 4;
  const int c16  = lane & 15;
  const int h7   = c16 & 7;
  const int wm   = wave >> 2;        // 0..1
  const int wn   = wave & 3;         // 0..3
  const int nwg  = gridDim.x;
  const int bid  = blockIdx.x;
  const int wgid = (bid & 7) * (nwg >> 3) + (bid >> 3);
  const int mat  = wgid >> 6;        // K-slice 0..3
  const int rem  = wgid & 63;
  const int m0   = (rem & 7) * 256;
  const int n0   = ((rem >> 3) & 7) * 256;
  const int kbeg = mat * (DM / 4);
  const int NT   = DM / 4 / 64;      // 8 K-tiles

  const int srow = lane >> 3;
  const int sg   = (lane & 7) ^ srow;
  auto stage = [&](int d, int k0) {
    const size_t koff = (size_t)k0 + sg * 8;
#pragma unroll
    for (int c = 0; c < 4; ++c) {
      const int rb = wave * 32 + c * 8;
      async_copy16(A + (size_t)(m0 + rb + srow) * DM + koff, &Ab[d][rb * 64]);
      async_copy16(B0 + (size_t)(n0 + rb + srow) * DM + koff, &Bb[d][rb * 64]);
    }
  };

  const f32x4 fzero = {0.f, 0.f, 0.f, 0.f};
  f32x4 acc[8][4];
#pragma unroll
  for (int i = 0; i < 8; ++i)
#pragma unroll
    for (int j = 0; j < 4; ++j) acc[i][j] = fzero;

  stage(0, kbeg);
  asm volatile("s_waitcnt vmcnt(0)" ::: "memory");
  __builtin_amdgcn_s_barrier();

  for (int kt = 0; kt < NT; ++kt) {
    const int cur = kt & 1;
    if (kt + 1 < NT) stage(cur ^ 1, kbeg + (kt + 1) * 64);
    const u16t* Abuf = Ab[cur];
    const u16t* Bbuf = Bb[cur];
    __builtin_amdgcn_s_setprio(1);
#pragma unroll
    for (int ks = 0; ks < 2; ++ks) {
      short8 af[8], bfr[4];
#pragma unroll
      for (int i = 0; i < 8; ++i) {
        const int row = wm * 128 + i * 16 + c16;
        af[i] = *(const short8*)(Abuf + row * 64 + (((ks * 4 + quad) ^ h7) * 8));
      }
#pragma unroll
      for (int nt = 0; nt < 4; ++nt) {
        const int row = wn * 64 + nt * 16 + c16;
        bfr[nt] = *(const short8*)(Bbuf + row * 64 + (((ks * 4 + quad) ^ h7) * 8));
      }
#pragma unroll
      for (int i = 0; i < 8; ++i)
#pragma unroll
        for (int nt = 0; nt < 4; ++nt)
          acc[i][nt] =
              __builtin_amdgcn_mfma_f32_16x16x32_bf16(af[i], bfr[nt], acc[i][nt], 0, 0, 0);
    }
    __builtin_amdgcn_s_setprio(0);
    asm volatile("s_waitcnt vmcnt(0)" ::: "memory");
    __builtin_amdgcn_s_barrier();
  }

  u16t* P = (mat == 0) ? P0 : (mat == 1) ? P1 : (mat == 2) ? P2 : P3;
#pragma unroll
  for (int mt = 0; mt < 8; ++mt) {
#pragma unroll
    for (int r = 0; r < 4; ++r) {
      const int row = m0 + wm * 128 + mt * 16 + quad * 4 + r;
      const size_t base = (size_t)row * DM;
#pragma unroll
      for (int nt = 0; nt < 4; ++nt) {
        const int col = n0 + wn * 64 + nt * 16 + c16;
        P[base + col] = f2bf(acc[mt][nt][r]);
      }
    }
  }
}

// ---------------- combine: out = x + mask_row * (P0+P1+P2+P3), bf16 partials ------------
__global__ __launch_bounds__(256) void combine4_kernel(const u16t* __restrict__ P0,
                                                       const u16t* __restrict__ P1,
                                                       const u16t* __restrict__ P2,
                                                       const u16t* __restrict__ P3,
                                                       const float* __restrict__ x,
                                                       const int* __restrict__ am,
                                                       float* __restrict__ out) {
  const size_t idx = ((size_t)blockIdx.x * 256 + threadIdx.x) * 4;
  const int row = (int)(idx >> 11);           // idx / DM
  const float mk = (am[row] != 0) ? 1.f : 0.f;
  const u16x4 a = *(const u16x4*)(P0 + idx);
  const u16x4 b = *(const u16x4*)(P1 + idx);
  const u16x4 c = *(const u16x4*)(P2 + idx);
  const u16x4 d = *(const u16x4*)(P3 + idx);
  const f32x4 xr = *(const f32x4*)(x + idx);
  f32x4 o;
#pragma unroll
  for (int i = 0; i < 4; ++i)
    o[i] = xr[i] + mk * ((bf2f(a[i]) + bf2f(b[i])) + (bf2f(c[i]) + bf2f(d[i])));
  *(f32x4*)(out + idx) = o;
}

// ---------------- Flash attention (causal), KVBLK=64, double-buffered 2-phase ----------
// Round-9 rework: old version staged K/V with issue->syncthreads (vmcnt(0) drain) ->
// compute — ZERO overlap of staging with compute. New: KVBLK=64 so K/V double-buffer
// fits in 64 KB (+8 KB P = 72 KB, keeps 2 blocks/CU); per tile {stage kt+1; compute
// from cur; vmcnt(0); barrier} — the proven GEMM 2-phase. P chunk granule-swizzled by
// quad (write 8->4-way, read 8->2-way bank conflicts).
__global__ __launch_bounds__(256) void attn_kernel(const u16t* __restrict__ Q,
                                                   const u16t* __restrict__ K,
                                                   const u16t* __restrict__ Vt,
                                                   const int* __restrict__ am,
                                                   u16t* __restrict__ O) {
  __shared__ u16t Klds[2][64 * 128];   // [key][d], granule-swizzled, 2 x 16 KB
  __shared__ u16t Vlds[2][128 * 64];   // [d][key], granule-swizzled, 2 x 16 KB
  __shared__ u16t Plds[4][1024];       // per-wave P: 2 chunks of 16x32, 8 KB
  const int wave = threadIdx.x >> 6;
  const int lane = threadIdx.x & 63;
  const int x    = blockIdx.x;
  const int half = x >> 8;                  // 0: qt 31..16, 1: qt 0..15
  const int idx  = x & 255;
  const int head = idx & (NH - 1);
  const int grp  = idx >> 4;                // 0..15
  const int qt   = half ? grp : (TS / 64 - 1 - grp);
  const int q0   = qt * 64 + wave * 16;
  const int quad = lane >> 4;
  const int c16  = lane & 15;
  const u16t* Qh  = Q + head * DH;
  const u16t* Kh  = K + head * DH;
  const u16t* Vth = Vt + (size_t)head * DH * TS;
  u16t* Pw = Plds[wave];

  const int krow = lane >> 4;               // 0..3 row within K chunk (4 rows x 16 gran)
  const int kg_s = lane & 15;               // K granule slot
  const int vrow = lane >> 3;               // 0..7 row within V chunk (8 rows x 8 gran)
  const int vg_s = (lane & 7) ^ vrow;       // pre-swizzled V granule (involution)

  // K: 16 chunks of 1KB (4 rows x 128B); V: 16 chunks of 1KB (8 rows x 64B x ... 8 gran)
  auto stageKV = [&](int d, int k0) {
#pragma unroll
    for (int c = 0; c < 4; ++c) {
      const int ch = wave * 4 + c;          // 0..15
      const int kr = 4 * ch + krow;         // 0..63
      async_copy16(Kh + (size_t)(k0 + kr) * DM + ((kg_s ^ (kr & 15)) * 8),
                   Klds[d] + ch * 512);
      const int vr = 8 * ch + vrow;         // 0..127
      async_copy16(Vth + (size_t)vr * TS + k0 + vg_s * 8, Vlds[d] + ch * 512);
    }
  };

  short8 qf[4];
#pragma unroll
  for (int dc = 0; dc < 4; ++dc)
    qf[dc] = *(const short8*)(Qh + (size_t)(q0 + c16) * DM + dc * 32 + quad * 8);

  const f32x4 fzero = {0.f, 0.f, 0.f, 0.f};
  float m_run[4], l_run[4];
  f32x4 o_acc[8];
#pragma unroll
  for (int r = 0; r < 4; ++r) { m_run[r] = -1e30f; l_run[r] = 0.f; }
#pragma unroll
  for (int nt = 0; nt < 8; ++nt) o_acc[nt] = fzero;

  const float scale = 0.08838834764831845f;  // 1/sqrt(128)
  const int ntiles = qt + 1;                 // 64-key tiles covering keys 0..qt*64+63

  stageKV(0, 0);
  asm volatile("s_waitcnt vmcnt(0)" ::: "memory");
  __builtin_amdgcn_s_barrier();

  for (int kt = 0; kt < ntiles; ++kt) {
    const int cur = kt & 1;
    const int k0 = kt * 64;
    if (kt + 1 < ntiles) stageKV(cur ^ 1, k0 + 64);   // prefetch under compute

    f32x4 s[4];
#pragma unroll
    for (int ns = 0; ns < 4; ++ns) {
      f32x4 sa = fzero;
      const int rr = ns * 16 + c16;
#pragma unroll
      for (int dc = 0; dc < 4; ++dc) {
        short8 kf = *(const short8*)(Klds[cur] + rr * 128 + (((dc * 4 + quad) ^ c16) * 8));
        sa = __builtin_amdgcn_mfma_f32_16x16x32_bf16(qf[dc], kf, sa, 0, 0, 0);
      }
      s[ns] = sa;
    }

    float pv[4][4], tmax[4];
#pragma unroll
    for (int r = 0; r < 4; ++r) tmax[r] = -1e30f;
#pragma unroll
    for (int ns = 0; ns < 4; ++ns) {
      const int key = k0 + ns * 16 + c16;
      const bool kok = (am[key] != 0);
#pragma unroll
      for (int r = 0; r < 4; ++r) {
        const int qrow = q0 + quad * 4 + r;
        float v = s[ns][r] * scale;
        if (key > qrow || !kok) v = -1e30f;
        pv[ns][r] = v;
        tmax[r] = fmaxf(tmax[r], v);
      }
    }
    float alpha[4];
#pragma unroll
    for (int r = 0; r < 4; ++r) {
      const float mn = fmaxf(m_run[r], row16_max(tmax[r]));
      alpha[r] = __expf(m_run[r] - mn);
      m_run[r] = mn;
      float rs = 0.f;
#pragma unroll
      for (int ns = 0; ns < 4; ++ns) {
        const float e = __expf(pv[ns][r] - mn);
        pv[ns][r] = e;
        rs += e;
      }
      l_run[r] = l_run[r] * alpha[r] + row16_sum(rs);
    }

    // P store: chunk ns>>1, row quad*4+r, col (ns&1)*16+c16; granule XOR'd by quad.
#pragma unroll
    for (int ns = 0; ns < 4; ++ns)
#pragma unroll
      for (int r = 0; r < 4; ++r)
        Pw[(ns >> 1) * 512 + (quad * 4 + r) * 32 +
           ((((ns & 1) * 2 + (c16 >> 3)) ^ quad) & 3) * 8 + (c16 & 7)] = f2bf(pv[ns][r]);
    asm volatile("s_waitcnt lgkmcnt(0)" ::: "memory");
    short8 pf[2];
#pragma unroll
    for (int c = 0; c < 2; ++c)
      pf[c] = *(const short8*)(Pw + c * 512 + c16 * 32 + ((quad ^ (c16 >> 2)) & 3) * 8);

#pragma unroll
    for (int nt = 0; nt < 8; ++nt)
#pragma unroll
      for (int r = 0; r < 4; ++r) o_acc[nt][r] *= alpha[r];
#pragma unroll
    for (int nt = 0; nt < 8; ++nt) {
      const int rr = nt * 16 + c16;
#pragma unroll
      for (int c = 0; c < 2; ++c) {
        short8 vf = *(const short8*)(Vlds[cur] + rr * 64 + (((c * 4 + quad) ^ (c16 & 7)) * 8));
        o_acc[nt] = __builtin_amdgcn_mfma_f32_16x16x32_bf16(pf[c], vf, o_acc[nt], 0, 0, 0);
      }
    }

    asm volatile("s_waitcnt vmcnt(0)" ::: "memory");   // prefetch landed; cur consumed
    __builtin_amdgcn_s_barrier();
  }

#pragma unroll
  for (int r = 0; r < 4; ++r) {
    const float inv = 1.0f / fmaxf(l_run[r], 1e-20f);
    const int qrow = q0 + quad * 4 + r;
#pragma unroll
    for (int nt = 0; nt < 8; ++nt)
      O[(size_t)qrow * DM + head * DH + nt * 16 + c16] = f2bf(o_acc[nt][r] * inv);
  }
}

extern "C" void kernel_launch(void* const* d_in, const int* in_sizes, int n_in,
                              void* d_out, int out_size, void* d_ws, size_t ws_size,
                              hipStream_t stream) {
  const float* x    = (const float*)d_in[0];
  const float* cosb = (const float*)d_in[1];
  const float* sinb = (const float*)d_in[2];
  const int*   am   = (const int*)d_in[3];
  const float* lnw  = (const float*)d_in[4];
  const float* Wq   = (const float*)d_in[5];
  const float* Wk   = (const float*)d_in[6];
  const float* Wv   = (const float*)d_in[7];
  const float* Wo   = (const float*)d_in[8];
  float* out = (float*)d_out;

  u16t* h    = (u16t*)d_ws;                 // (T, D) bf16   [0, 8 MB)   ; out-proj P0
  u16t* Q    = h + (size_t)TS * DM;         //               [8, 16)     ; out-proj P1
  u16t* K    = Q + (size_t)TS * DM;         //               [16, 24)    ; out-proj P2
  u16t* Vt   = K + (size_t)TS * DM;         //               [24, 32)    ; out-proj P3
  u16t* attn = Vt + (size_t)TS * DM;        //               [32, 40)
  u16t* Wb   = attn + (size_t)TS * DM;      // 4 x (D, D)    [40, 72)
  u16t* Wqb = Wb;
  u16t* Wkb = Wb + (size_t)DM * DM;
  u16t* Wvb = Wb + 2 * (size_t)DM * DM;
  u16t* Wob = Wb + 3 * (size_t)DM * DM;

  cast_rms_kernel<<<16384 + TS, 256, 0, stream>>>(Wq, Wk, Wv, Wo, Wb, x, lnw, h);
  // fused QKV: 16x16 tiles = 256 blocks (1/CU), all 3 matrices per block
  gemm_qkv<<<256, 512, 0, stream>>>(h, Wqb, Wkb, Wvb, Q, K, Vt, cosb, sinb);
  attn_kernel<<<NH * (TS / 64), 256, 0, stream>>>(Q, K, Vt, am, attn);
  // out-proj: 64 tiles x split-K=4 = 256 blocks; bf16 partials into dead h/Q/K/Vt
  gemm_out<<<256, 512, 0, stream>>>(attn, Wob, h, Q, K, Vt);
  combine4_kernel<<<(TS * DM / 4) / 256, 256, 0, stream>>>(h, Q, K, Vt, x, am, out);
}

// Round 12
// 283.481 us; speedup vs baseline: 1.0550x; 1.0550x over previous
//
#include <hip/hip_runtime.h>
#include <stdint.h>

#define TS 2048
#define DM 2048
#define NH 16
#define DH 128

typedef unsigned short u16t;
typedef __attribute__((ext_vector_type(8))) short short8;
typedef __attribute__((ext_vector_type(4))) float f32x4;
typedef __attribute__((ext_vector_type(4))) unsigned int u32x4;
typedef __attribute__((ext_vector_type(4))) unsigned short u16x4;

__device__ __forceinline__ float bf2f(u16t b) {
  return __uint_as_float(((unsigned int)b) << 16);
}
__device__ __forceinline__ u16t f2bf(float f) {
  unsigned int u = __float_as_uint(f);
  u += 0x7FFFu + ((u >> 16) & 1u);   // round-to-nearest-even
  return (u16t)(u >> 16);
}

// async global->LDS, 16B per lane. LDS dest = wave-uniform base + lane*16.
__device__ __forceinline__ void async_copy16(const u16t* g, u16t* l) {
  __builtin_amdgcn_global_load_lds((const __attribute__((address_space(1))) void*)g,
                                   (__attribute__((address_space(3))) void*)l, 16, 0, 0);
}

// DPP row_ror within 16-lane rows: pure-VALU cross-lane (vs ds_bpermute for __shfl).
#define DPP_ROR_F(x, n) __uint_as_float(__builtin_amdgcn_update_dpp( \
    0, (int)__float_as_uint(x), 0x120 | (n), 0xF, 0xF, true))

__device__ __forceinline__ float row16_max(float x) {
  x = fmaxf(x, DPP_ROR_F(x, 8));
  x = fmaxf(x, DPP_ROR_F(x, 4));
  x = fmaxf(x, DPP_ROR_F(x, 2));
  x = fmaxf(x, DPP_ROR_F(x, 1));
  return x;
}
__device__ __forceinline__ float row16_sum(float x) {
  x += DPP_ROR_F(x, 8);
  x += DPP_ROR_F(x, 4);
  x += DPP_ROR_F(x, 2);
  x += DPP_ROR_F(x, 1);
  return x;
}

// ---------------- fused: fp32->bf16 weight cast (blocks 0..16383) + RMSNorm (rest) ----
// Wq/Wk rows are PERMUTED within each head at cast time so that RoPE partners
// (d, d+64) land at columns (p, p+16): p = (d>>4)*32 + (d&15) [+16 for d>=64].
// In the GEMM C-fragment, col and col+16 are the same lane / adjacent nt register,
// so RoPE becomes a pure in-register epilogue op. Q.K dot is invariant (same perm).
__global__ __launch_bounds__(256) void cast_rms_kernel(const float* __restrict__ W0,
                                                       const float* __restrict__ W1,
                                                       const float* __restrict__ W2,
                                                       const float* __restrict__ W3,
                                                       u16t* __restrict__ outw,
                                                       const float* __restrict__ x,
                                                       const float* __restrict__ lnw,
                                                       u16t* __restrict__ h) {
  if (blockIdx.x < 16384) {
    const int idx = blockIdx.x * 256 + threadIdx.x;   // 4M threads, 4 elems each
    const int mat = idx >> 20;
    const size_t off = (size_t)(idx & 0xFFFFF) * 4;
    const float* W = (mat == 0) ? W0 : (mat == 1) ? W1 : (mat == 2) ? W2 : W3;
    const f32x4 v = *(const f32x4*)(W + off);
    size_t dstoff = off;
    if (mat < 2) {   // permute output-feature rows of Wq, Wk
      const int row = (int)(off >> 11);
      const int col = (int)(off & 2047);
      const int d = row & 127;
      const int e = d & 63;
      const int p = ((e >> 4) * 32 + (e & 15)) + ((d >> 6) << 4);
      dstoff = ((size_t)((row & ~127) | p) << 11) | (size_t)col;
    }
    union { u16t s[4]; uint64_t u; } o;
#pragma unroll
    for (int i = 0; i < 4; ++i) o.s[i] = f2bf(v[i]);
    *(uint64_t*)(outw + (size_t)mat * (DM * DM) + dstoff) = o.u;
    return;
  }
  const int row = blockIdx.x - 16384;
  const int tid = threadIdx.x;
  const float* xr = x + (size_t)row * DM + tid * 8;
  f32x4 v0 = *(const f32x4*)(xr);
  f32x4 v1 = *(const f32x4*)(xr + 4);
  float f[8];
#pragma unroll
  for (int i = 0; i < 4; ++i) { f[i] = v0[i]; f[i + 4] = v1[i]; }
  float ss = 0.f;
#pragma unroll
  for (int i = 0; i < 8; ++i) ss += f[i] * f[i];
#pragma unroll
  for (int off = 1; off < 64; off <<= 1) ss += __shfl_xor(ss, off, 64);
  __shared__ float wsum[4];
  if ((tid & 63) == 0) wsum[tid >> 6] = ss;
  __syncthreads();
  float tot = wsum[0] + wsum[1] + wsum[2] + wsum[3];
  float rs = rsqrtf(tot * (1.0f / DM) + 1e-5f);
  f32x4 w0 = *(const f32x4*)(lnw + tid * 8);
  f32x4 w1 = *(const f32x4*)(lnw + tid * 8 + 4);
  u32x4 o;
#pragma unroll
  for (int i = 0; i < 4; ++i) {
    unsigned int lo = f2bf(f[2 * i]     * ((2 * i     < 4) ? w0[2 * i]     : w1[2 * i - 4]) * rs);
    unsigned int hi = f2bf(f[2 * i + 1] * ((2 * i + 1 < 4) ? w0[2 * i + 1] : w1[2 * i - 3]) * rs);
    o[i] = lo | (hi << 16);
  }
  *(u32x4*)(h + (size_t)row * DM + tid * 8) = o;
}

// ---------------- fused QKV GEMM: one block computes Q,K,V for a 128x128 tile ----------
// (verified round 9: 78.6 us, 655 TF, conflicts 0 — frozen as control)
__global__ __launch_bounds__(512, 2) void gemm_qkv(
    const u16t* __restrict__ A,
    const u16t* __restrict__ B0, const u16t* __restrict__ B1, const u16t* __restrict__ B2,
    u16t* __restrict__ Cq, u16t* __restrict__ Ck, u16t* __restrict__ Cv,
    const float* __restrict__ cosb, const float* __restrict__ sinb) {
  __shared__ u16t Ab[2][128 * 64];      // 32 KB
  __shared__ u16t Bb[3][2][128 * 64];   // 96 KB
  const int tid  = threadIdx.x;
  const int wave = tid >> 6;
  const int lane = tid & 63;
  const int quad = lane >> 4;
  const int c16  = lane & 15;
  const int h7   = c16 & 7;
  const int wm   = wave >> 2;        // 0..1  (token half: 64 rows)
  const int wn   = wave & 3;         // 0..3  (feature quarter: 32 cols)
  const int bid  = blockIdx.x;
  const int wgid = (bid & 7) * 32 + (bid >> 3);
  const int m0   = (wgid & 15) * 128;
  const int n0   = (wgid >> 4) * 128;

  const int srow = lane >> 3;               // 0..7
  const int sg   = (lane & 7) ^ srow;       // permuted 16B granule
  auto stage = [&](int d, int k0) {
    const size_t koff = (size_t)k0 + sg * 8;
#pragma unroll
    for (int c = 0; c < 2; ++c) {
      const int rb = wave * 16 + c * 8;     // chunk row base 0..127 (multiple of 8)
      async_copy16(A  + (size_t)(m0 + rb + srow) * DM + koff, &Ab[d][rb * 64]);
      async_copy16(B0 + (size_t)(n0 + rb + srow) * DM + koff, &Bb[0][d][rb * 64]);
      async_copy16(B1 + (size_t)(n0 + rb + srow) * DM + koff, &Bb[1][d][rb * 64]);
      async_copy16(B2 + (size_t)(n0 + rb + srow) * DM + koff, &Bb[2][d][rb * 64]);
    }
  };

  const f32x4 fzero = {0.f, 0.f, 0.f, 0.f};
  f32x4 acc[3][4][2];   // [mat][mt][nt] -> 96 VGPR
#pragma unroll
  for (int m = 0; m < 3; ++m)
#pragma unroll
    for (int i = 0; i < 4; ++i)
#pragma unroll
      for (int j = 0; j < 2; ++j) acc[m][i][j] = fzero;

  stage(0, 0);
  asm volatile("s_waitcnt vmcnt(0)" ::: "memory");
  __builtin_amdgcn_s_barrier();

  for (int kt = 0; kt < DM / 64; ++kt) {
    const int cur = kt & 1;
    if (kt + 1 < DM / 64) stage(cur ^ 1, (kt + 1) * 64);   // prefetch under compute
    const u16t* Abuf = Ab[cur];
    __builtin_amdgcn_s_setprio(1);
#pragma unroll
    for (int ks = 0; ks < 2; ++ks) {       // two K=32 halves
      const int gsw = ((ks * 4 + quad) ^ h7) * 8;
      short8 af[4], bfr[3][2];
#pragma unroll
      for (int i = 0; i < 4; ++i)
        af[i] = *(const short8*)(Abuf + (wm * 64 + i * 16 + c16) * 64 + gsw);
#pragma unroll
      for (int m = 0; m < 3; ++m)
#pragma unroll
        for (int nt = 0; nt < 2; ++nt)
          bfr[m][nt] = *(const short8*)(&Bb[m][cur][0] + (wn * 32 + nt * 16 + c16) * 64 + gsw);
#pragma unroll
      for (int m = 0; m < 3; ++m)
#pragma unroll
        for (int i = 0; i < 4; ++i)
#pragma unroll
          for (int nt = 0; nt < 2; ++nt)
            acc[m][i][nt] =
                __builtin_amdgcn_mfma_f32_16x16x32_bf16(af[i], bfr[m][nt], acc[m][i][nt], 0, 0, 0);
    }
    __builtin_amdgcn_s_setprio(0);
    asm volatile("s_waitcnt vmcnt(0)" ::: "memory");
    __builtin_amdgcn_s_barrier();
  }

  // Q/K with fused RoPE: each wave's cols are (p, p+16) pairs, p = wn*32 + c16.
#pragma unroll
  for (int mat = 0; mat < 2; ++mat) {
    u16t* C = mat ? Ck : Cq;
#pragma unroll
    for (int mt = 0; mt < 4; ++mt) {
#pragma unroll
      for (int r = 0; r < 4; ++r) {
        const int row = m0 + wm * 64 + mt * 16 + quad * 4 + r;   // = token t
        const size_t base = (size_t)row * DM;
        const int col = n0 + wn * 32 + c16;
        const int p = col & 127;
        const int dorig = ((p >> 5) << 4) + c16;
        const float cv = cosb[row * DH + dorig];
        const float sv = sinb[row * DH + dorig];
        const float x1 = acc[mat][mt][0][r];
        const float x2 = acc[mat][mt][1][r];
        C[base + col]      = f2bf(x1 * cv - x2 * sv);
        C[base + col + 16] = f2bf(x2 * cv + x1 * sv);
      }
    }
  }
  // V: transposed store
#pragma unroll
  for (int mt = 0; mt < 4; ++mt) {
#pragma unroll
    for (int r = 0; r < 4; ++r) {
      const int row = m0 + wm * 64 + mt * 16 + quad * 4 + r;
#pragma unroll
      for (int nt = 0; nt < 2; ++nt) {
        const int col = n0 + wn * 32 + nt * 16 + c16;
        Cv[(size_t)col * TS + row] = f2bf(acc[2][mt][nt][r]);
      }
    }
  }
}

// ---------------- out-proj GEMM: 128x128 tile, FULL K, fused residual epilogue --------
// Replaces split-K=4 (256^2 tiles) + combine4. 16x16 = 256 blocks = 1/CU (64 KB LDS ->
// 2 blocks/CU co-residency), 8 waves (2M x 4N), same verified 2-phase loop + swizzle
// as gemm_qkv. Epilogue: out = x + mask_row * acc, fp32 store direct — no partials,
// no combine kernel.
__global__ __launch_bounds__(512, 2) void gemm_out(
    const u16t* __restrict__ A, const u16t* __restrict__ B0,
    const float* __restrict__ xres, const int* __restrict__ am,
    float* __restrict__ out) {
  __shared__ u16t Ab[2][128 * 64];   // 32 KB
  __shared__ u16t Bb[2][128 * 64];   // 32 KB
  const int tid  = threadIdx.x;
  const int wave = tid >> 6;
  const int lane = tid & 63;
  const int quad = lane >> 4;
  const int c16  = lane & 15;
  const int h7   = c16 & 7;
  const int wm   = wave >> 2;        // 0..1  (row half: 64 rows)
  const int wn   = wave & 3;         // 0..3  (col quarter: 32 cols)
  const int bid  = blockIdx.x;
  const int wgid = (bid & 7) * 32 + (bid >> 3);   // XCD swizzle, bijective at 256
  const int m0   = (wgid & 15) * 128;
  const int n0   = (wgid >> 4) * 128;

  const int srow = lane >> 3;
  const int sg   = (lane & 7) ^ srow;
  auto stage = [&](int d, int k0) {
    const size_t koff = (size_t)k0 + sg * 8;
#pragma unroll
    for (int c = 0; c < 2; ++c) {
      const int rb = wave * 16 + c * 8;
      async_copy16(A  + (size_t)(m0 + rb + srow) * DM + koff, &Ab[d][rb * 64]);
      async_copy16(B0 + (size_t)(n0 + rb + srow) * DM + koff, &Bb[d][rb * 64]);
    }
  };

  const f32x4 fzero = {0.f, 0.f, 0.f, 0.f};
  f32x4 acc[4][2];
#pragma unroll
  for (int i = 0; i < 4; ++i)
#pragma unroll
    for (int j = 0; j < 2; ++j) acc[i][j] = fzero;

  stage(0, 0);
  asm volatile("s_waitcnt vmcnt(0)" ::: "memory");
  __builtin_amdgcn_s_barrier();

  for (int kt = 0; kt < DM / 64; ++kt) {
    const int cur = kt & 1;
    if (kt + 1 < DM / 64) stage(cur ^ 1, (kt + 1) * 64);
    const u16t* Abuf = Ab[cur];
    const u16t* Bbuf = Bb[cur];
    __builtin_amdgcn_s_setprio(1);
#pragma unroll
    for (int ks = 0; ks < 2; ++ks) {
      const int gsw = ((ks * 4 + quad) ^ h7) * 8;
      short8 af[4], bfr[2];
#pragma unroll
      for (int i = 0; i < 4; ++i)
        af[i] = *(const short8*)(Abuf + (wm * 64 + i * 16 + c16) * 64 + gsw);
#pragma unroll
      for (int nt = 0; nt < 2; ++nt)
        bfr[nt] = *(const short8*)(Bbuf + (wn * 32 + nt * 16 + c16) * 64 + gsw);
#pragma unroll
      for (int i = 0; i < 4; ++i)
#pragma unroll
        for (int nt = 0; nt < 2; ++nt)
          acc[i][nt] =
              __builtin_amdgcn_mfma_f32_16x16x32_bf16(af[i], bfr[nt], acc[i][nt], 0, 0, 0);
    }
    __builtin_amdgcn_s_setprio(0);
    asm volatile("s_waitcnt vmcnt(0)" ::: "memory");
    __builtin_amdgcn_s_barrier();
  }

  // fused residual + row-mask epilogue, fp32 store direct to output
#pragma unroll
  for (int mt = 0; mt < 4; ++mt) {
#pragma unroll
    for (int r = 0; r < 4; ++r) {
      const int row = m0 + wm * 64 + mt * 16 + quad * 4 + r;
      const float mk = (am[row] != 0) ? 1.f : 0.f;
      const size_t base = (size_t)row * DM;
#pragma unroll
      for (int nt = 0; nt < 2; ++nt) {
        const int col = n0 + wn * 32 + nt * 16 + c16;
        out[base + col] = xres[base + col] + mk * acc[mt][nt][r];
      }
    }
  }
}

// ---------------- Flash attention (causal), LDS-staged K/V, 128-key tiles ----------------
// (round-5 version, verified fast — reverted after round-10's KVBLK=64 regression)
__global__ __launch_bounds__(256) void attn_kernel(const u16t* __restrict__ Q,
                                                   const u16t* __restrict__ K,
                                                   const u16t* __restrict__ Vt,
                                                   const int* __restrict__ am,
                                                   u16t* __restrict__ O) {
  __shared__ u16t Klds[128 * 128];   // [key][d], swizzled granules, 32 KB
  __shared__ u16t Vlds[128 * 128];   // [d][key], swizzled granules, 32 KB
  __shared__ u16t Plds[4][2048];     // per-wave P: 4 chunks of 16x32, 16 KB
  const int wave = threadIdx.x >> 6;
  const int lane = threadIdx.x & 63;
  const int x    = blockIdx.x;
  const int half = x >> 8;                  // 0: qt 31..16, 1: qt 0..15
  const int idx  = x & 255;
  const int head = idx & (NH - 1);
  const int grp  = idx >> 4;                // 0..15
  const int qt   = half ? grp : (TS / 64 - 1 - grp);
  const int q0   = qt * 64 + wave * 16;
  const int quad = lane >> 4;
  const int c16  = lane & 15;
  const u16t* Qh  = Q + head * DH;
  const u16t* Kh  = K + head * DH;
  const u16t* Vth = Vt + (size_t)head * DH * TS;
  u16t* Pw = Plds[wave];

  const int row_s = (lane >> 4);    // 0..3 row within chunk
  const int g_s   = (lane & 15);    // granule slot

  short8 qf[4];
#pragma unroll
  for (int dc = 0; dc < 4; ++dc)
    qf[dc] = *(const short8*)(Qh + (size_t)(q0 + c16) * DM + dc * 32 + quad * 8);

  const f32x4 fzero = {0.f, 0.f, 0.f, 0.f};
  float m_run[4], l_run[4];
  f32x4 o_acc[8];
#pragma unroll
  for (int r = 0; r < 4; ++r) { m_run[r] = -1e30f; l_run[r] = 0.f; }
#pragma unroll
  for (int nt = 0; nt < 8; ++nt) o_acc[nt] = fzero;

  const float scale = 0.08838834764831845f;  // 1/sqrt(128)
  const int ntiles = (qt * 64 + 191) >> 7;   // 128-wide tiles covering keys 0..q0+63

  for (int kt = 0; kt < ntiles; ++kt) {
    const int k0 = kt * 128;
    __syncthreads();
#pragma unroll
    for (int c = 0; c < 8; ++c) {
      const int ch = wave * 8 + c;
      const int r  = 4 * ch + row_s;           // 0..127
      const int g  = g_s ^ (r & 15);
      async_copy16(Kh + (size_t)(k0 + r) * DM + g * 8, Klds + ch * 512);
      async_copy16(Vth + (size_t)r * TS + k0 + g * 8, Vlds + ch * 512);
    }
    __syncthreads();

    f32x4 s[8];
#pragma unroll
    for (int ns = 0; ns < 8; ++ns) {
      f32x4 sa = fzero;
      const int rr = ns * 16 + c16;
#pragma unroll
      for (int dc = 0; dc < 4; ++dc) {
        short8 kf = *(const short8*)(Klds + rr * 128 + (((dc * 4 + quad) ^ c16) * 8));
        sa = __builtin_amdgcn_mfma_f32_16x16x32_bf16(qf[dc], kf, sa, 0, 0, 0);
      }
      s[ns] = sa;
    }

    float pv[8][4], tmax[4];
#pragma unroll
    for (int r = 0; r < 4; ++r) tmax[r] = -1e30f;
#pragma unroll
    for (int ns = 0; ns < 8; ++ns) {
      const int key = k0 + ns * 16 + c16;
      const bool kok = (am[key] != 0);
#pragma unroll
      for (int r = 0; r < 4; ++r) {
        const int qrow = q0 + quad * 4 + r;
        float v = s[ns][r] * scale;
        if (key > qrow || !kok) v = -1e30f;
        pv[ns][r] = v;
        tmax[r] = fmaxf(tmax[r], v);
      }
    }
    float alpha[4], rsum[4];
#pragma unroll
    for (int r = 0; r < 4; ++r) {
      const float mn = fmaxf(m_run[r], row16_max(tmax[r]));
      alpha[r] = __expf(m_run[r] - mn);
      m_run[r] = mn;
      float rs = 0.f;
#pragma unroll
      for (int ns = 0; ns < 8; ++ns) {
        const float e = __expf(pv[ns][r] - mn);
        pv[ns][r] = e;
        rs += e;
      }
      rsum[r] = row16_sum(rs);
      l_run[r] = l_run[r] * alpha[r] + rsum[r];
    }

#pragma unroll
    for (int ns = 0; ns < 8; ++ns)
#pragma unroll
      for (int r = 0; r < 4; ++r)
        Pw[(ns >> 1) * 512 + (quad * 4 + r) * 32 + (ns & 1) * 16 + c16] = f2bf(pv[ns][r]);
    asm volatile("s_waitcnt lgkmcnt(0)" ::: "memory");
    short8 pf[4];
#pragma unroll
    for (int c = 0; c < 4; ++c)
      pf[c] = *(const short8*)(Pw + c * 512 + c16 * 32 + quad * 8);

#pragma unroll
    for (int nt = 0; nt < 8; ++nt)
#pragma unroll
      for (int r = 0; r < 4; ++r) o_acc[nt][r] *= alpha[r];
#pragma unroll
    for (int nt = 0; nt < 8; ++nt) {
      const int rr = nt * 16 + c16;
#pragma unroll
      for (int c = 0; c < 4; ++c) {
        short8 vf = *(const short8*)(Vlds + rr * 128 + (((c * 4 + quad) ^ c16) * 8));
        o_acc[nt] = __builtin_amdgcn_mfma_f32_16x16x32_bf16(pf[c], vf, o_acc[nt], 0, 0, 0);
      }
    }
  }

#pragma unroll
  for (int r = 0; r < 4; ++r) {
    const float inv = 1.0f / fmaxf(l_run[r], 1e-20f);
    const int qrow = q0 + quad * 4 + r;
#pragma unroll
    for (int nt = 0; nt < 8; ++nt)
      O[(size_t)qrow * DM + head * DH + nt * 16 + c16] = f2bf(o_acc[nt][r] * inv);
  }
}

extern "C" void kernel_launch(void* const* d_in, const int* in_sizes, int n_in,
                              void* d_out, int out_size, void* d_ws, size_t ws_size,
                              hipStream_t stream) {
  const float* x    = (const float*)d_in[0];
  const float* cosb = (const float*)d_in[1];
  const float* sinb = (const float*)d_in[2];
  const int*   am   = (const int*)d_in[3];
  const float* lnw  = (const float*)d_in[4];
  const float* Wq   = (const float*)d_in[5];
  const float* Wk   = (const float*)d_in[6];
  const float* Wv   = (const float*)d_in[7];
  const float* Wo   = (const float*)d_in[8];
  float* out = (float*)d_out;

  u16t* h    = (u16t*)d_ws;                 // (T, D) bf16   [0, 8 MB)
  u16t* Q    = h + (size_t)TS * DM;         //               [8, 16)
  u16t* K    = Q + (size_t)TS * DM;         //               [16, 24)
  u16t* Vt   = K + (size_t)TS * DM;         //               [24, 32)
  u16t* attn = Vt + (size_t)TS * DM;        //               [32, 40)
  u16t* Wb   = attn + (size_t)TS * DM;      // 4 x (D, D)    [40, 72)
  u16t* Wqb = Wb;
  u16t* Wkb = Wb + (size_t)DM * DM;
  u16t* Wvb = Wb + 2 * (size_t)DM * DM;
  u16t* Wob = Wb + 3 * (size_t)DM * DM;

  cast_rms_kernel<<<16384 + TS, 256, 0, stream>>>(Wq, Wk, Wv, Wo, Wb, x, lnw, h);
  // fused QKV: 16x16 tiles = 256 blocks (1/CU), all 3 matrices per block
  gemm_qkv<<<256, 512, 0, stream>>>(h, Wqb, Wkb, Wvb, Q, K, Vt, cosb, sinb);
  attn_kernel<<<NH * (TS / 64), 256, 0, stream>>>(Q, K, Vt, am, attn);
  // out-proj: 128x128 tiles, full K, fused residual+mask epilogue -> out (fp32)
  gemm_out<<<256, 512, 0, stream>>>(attn, Wob, x, am, out);
}

// Round 13
// 280.412 us; speedup vs baseline: 1.0666x; 1.0109x over previous
//
#include <hip/hip_runtime.h>
#include <stdint.h>

#define TS 2048
#define DM 2048
#define NH 16
#define DH 128

typedef unsigned short u16t;
typedef __attribute__((ext_vector_type(8))) short short8;
typedef __attribute__((ext_vector_type(4))) float f32x4;
typedef __attribute__((ext_vector_type(4))) unsigned int u32x4;
typedef __attribute__((ext_vector_type(4))) int i32x4;

__device__ __forceinline__ float bf2f(u16t b) {
  return __uint_as_float(((unsigned int)b) << 16);
}
__device__ __forceinline__ u16t f2bf(float f) {
  unsigned int u = __float_as_uint(f);
  u += 0x7FFFu + ((u >> 16) & 1u);   // round-to-nearest-even
  return (u16t)(u >> 16);
}

// async global->LDS, 16B per lane. LDS dest = wave-uniform base + lane*16.
__device__ __forceinline__ void async_copy16(const u16t* g, u16t* l) {
  __builtin_amdgcn_global_load_lds((const __attribute__((address_space(1))) void*)g,
                                   (__attribute__((address_space(3))) void*)l, 16, 0, 0);
}

// ---------------- fused: fp32->bf16 weight cast (blocks 0..16383) + RMSNorm (rest) ----
// Wq/Wk rows are PERMUTED within each head at cast time so that RoPE partners
// (d, d+64) land at columns (p, p+16): p = (d>>4)*32 + (d&15) [+16 for d>=64].
// In the GEMM C-fragment, col and col+16 are the same lane / adjacent nt register,
// so RoPE becomes a pure in-register epilogue op. Q.K dot is invariant (same perm).
__global__ __launch_bounds__(256) void cast_rms_kernel(const float* __restrict__ W0,
                                                       const float* __restrict__ W1,
                                                       const float* __restrict__ W2,
                                                       const float* __restrict__ W3,
                                                       u16t* __restrict__ outw,
                                                       const float* __restrict__ x,
                                                       const float* __restrict__ lnw,
                                                       u16t* __restrict__ h) {
  if (blockIdx.x < 16384) {
    const int idx = blockIdx.x * 256 + threadIdx.x;   // 4M threads, 4 elems each
    const int mat = idx >> 20;
    const size_t off = (size_t)(idx & 0xFFFFF) * 4;
    const float* W = (mat == 0) ? W0 : (mat == 1) ? W1 : (mat == 2) ? W2 : W3;
    const f32x4 v = *(const f32x4*)(W + off);
    size_t dstoff = off;
    if (mat < 2) {   // permute output-feature rows of Wq, Wk
      const int row = (int)(off >> 11);
      const int col = (int)(off & 2047);
      const int d = row & 127;
      const int e = d & 63;
      const int p = ((e >> 4) * 32 + (e & 15)) + ((d >> 6) << 4);
      dstoff = ((size_t)((row & ~127) | p) << 11) | (size_t)col;
    }
    union { u16t s[4]; uint64_t u; } o;
#pragma unroll
    for (int i = 0; i < 4; ++i) o.s[i] = f2bf(v[i]);
    *(uint64_t*)(outw + (size_t)mat * (DM * DM) + dstoff) = o.u;
    return;
  }
  const int row = blockIdx.x - 16384;
  const int tid = threadIdx.x;
  const float* xr = x + (size_t)row * DM + tid * 8;
  f32x4 v0 = *(const f32x4*)(xr);
  f32x4 v1 = *(const f32x4*)(xr + 4);
  float f[8];
#pragma unroll
  for (int i = 0; i < 4; ++i) { f[i] = v0[i]; f[i + 4] = v1[i]; }
  float ss = 0.f;
#pragma unroll
  for (int i = 0; i < 8; ++i) ss += f[i] * f[i];
#pragma unroll
  for (int off = 1; off < 64; off <<= 1) ss += __shfl_xor(ss, off, 64);
  __shared__ float wsum[4];
  if ((tid & 63) == 0) wsum[tid >> 6] = ss;
  __syncthreads();
  float tot = wsum[0] + wsum[1] + wsum[2] + wsum[3];
  float rs = rsqrtf(tot * (1.0f / DM) + 1e-5f);
  f32x4 w0 = *(const f32x4*)(lnw + tid * 8);
  f32x4 w1 = *(const f32x4*)(lnw + tid * 8 + 4);
  u32x4 o;
#pragma unroll
  for (int i = 0; i < 4; ++i) {
    unsigned int lo = f2bf(f[2 * i]     * ((2 * i     < 4) ? w0[2 * i]     : w1[2 * i - 4]) * rs);
    unsigned int hi = f2bf(f[2 * i + 1] * ((2 * i + 1 < 4) ? w0[2 * i + 1] : w1[2 * i - 3]) * rs);
    o[i] = lo | (hi << 16);
  }
  *(u32x4*)(h + (size_t)row * DM + tid * 8) = o;
}

// ---------------- fused QKV GEMM: one block computes Q,K,V for a 128x128 tile ----------
// (verified round 9/12: ~70-78 us, conflicts 0 — frozen as control)
__global__ __launch_bounds__(512, 2) void gemm_qkv(
    const u16t* __restrict__ A,
    const u16t* __restrict__ B0, const u16t* __restrict__ B1, const u16t* __restrict__ B2,
    u16t* __restrict__ Cq, u16t* __restrict__ Ck, u16t* __restrict__ Cv,
    const float* __restrict__ cosb, const float* __restrict__ sinb) {
  __shared__ u16t Ab[2][128 * 64];      // 32 KB
  __shared__ u16t Bb[3][2][128 * 64];   // 96 KB
  const int tid  = threadIdx.x;
  const int wave = tid >> 6;
  const int lane = tid & 63;
  const int quad = lane >> 4;
  const int c16  = lane & 15;
  const int h7   = c16 & 7;
  const int wm   = wave >> 2;        // 0..1  (token half: 64 rows)
  const int wn   = wave & 3;         // 0..3  (feature quarter: 32 cols)
  const int bid  = blockIdx.x;
  const int wgid = (bid & 7) * 32 + (bid >> 3);
  const int m0   = (wgid & 15) * 128;
  const int n0   = (wgid >> 4) * 128;

  const int srow = lane >> 3;               // 0..7
  const int sg   = (lane & 7) ^ srow;       // permuted 16B granule
  auto stage = [&](int d, int k0) {
    const size_t koff = (size_t)k0 + sg * 8;
#pragma unroll
    for (int c = 0; c < 2; ++c) {
      const int rb = wave * 16 + c * 8;     // chunk row base 0..127 (multiple of 8)
      async_copy16(A  + (size_t)(m0 + rb + srow) * DM + koff, &Ab[d][rb * 64]);
      async_copy16(B0 + (size_t)(n0 + rb + srow) * DM + koff, &Bb[0][d][rb * 64]);
      async_copy16(B1 + (size_t)(n0 + rb + srow) * DM + koff, &Bb[1][d][rb * 64]);
      async_copy16(B2 + (size_t)(n0 + rb + srow) * DM + koff, &Bb[2][d][rb * 64]);
    }
  };

  const f32x4 fzero = {0.f, 0.f, 0.f, 0.f};
  f32x4 acc[3][4][2];   // [mat][mt][nt] -> 96 VGPR
#pragma unroll
  for (int m = 0; m < 3; ++m)
#pragma unroll
    for (int i = 0; i < 4; ++i)
#pragma unroll
      for (int j = 0; j < 2; ++j) acc[m][i][j] = fzero;

  stage(0, 0);
  asm volatile("s_waitcnt vmcnt(0)" ::: "memory");
  __builtin_amdgcn_s_barrier();

  for (int kt = 0; kt < DM / 64; ++kt) {
    const int cur = kt & 1;
    if (kt + 1 < DM / 64) stage(cur ^ 1, (kt + 1) * 64);   // prefetch under compute
    const u16t* Abuf = Ab[cur];
    __builtin_amdgcn_s_setprio(1);
#pragma unroll
    for (int ks = 0; ks < 2; ++ks) {       // two K=32 halves
      const int gsw = ((ks * 4 + quad) ^ h7) * 8;
      short8 af[4], bfr[3][2];
#pragma unroll
      for (int i = 0; i < 4; ++i)
        af[i] = *(const short8*)(Abuf + (wm * 64 + i * 16 + c16) * 64 + gsw);
#pragma unroll
      for (int m = 0; m < 3; ++m)
#pragma unroll
        for (int nt = 0; nt < 2; ++nt)
          bfr[m][nt] = *(const short8*)(&Bb[m][cur][0] + (wn * 32 + nt * 16 + c16) * 64 + gsw);
#pragma unroll
      for (int m = 0; m < 3; ++m)
#pragma unroll
        for (int i = 0; i < 4; ++i)
#pragma unroll
          for (int nt = 0; nt < 2; ++nt)
            acc[m][i][nt] =
                __builtin_amdgcn_mfma_f32_16x16x32_bf16(af[i], bfr[m][nt], acc[m][i][nt], 0, 0, 0);
    }
    __builtin_amdgcn_s_setprio(0);
    asm volatile("s_waitcnt vmcnt(0)" ::: "memory");
    __builtin_amdgcn_s_barrier();
  }

  // Q/K with fused RoPE: each wave's cols are (p, p+16) pairs, p = wn*32 + c16.
#pragma unroll
  for (int mat = 0; mat < 2; ++mat) {
    u16t* C = mat ? Ck : Cq;
#pragma unroll
    for (int mt = 0; mt < 4; ++mt) {
#pragma unroll
      for (int r = 0; r < 4; ++r) {
        const int row = m0 + wm * 64 + mt * 16 + quad * 4 + r;   // = token t
        const size_t base = (size_t)row * DM;
        const int col = n0 + wn * 32 + c16;
        const int p = col & 127;
        const int dorig = ((p >> 5) << 4) + c16;
        const float cv = cosb[row * DH + dorig];
        const float sv = sinb[row * DH + dorig];
        const float x1 = acc[mat][mt][0][r];
        const float x2 = acc[mat][mt][1][r];
        C[base + col]      = f2bf(x1 * cv - x2 * sv);
        C[base + col + 16] = f2bf(x2 * cv + x1 * sv);
      }
    }
  }
  // V: transposed store
#pragma unroll
  for (int mt = 0; mt < 4; ++mt) {
#pragma unroll
    for (int r = 0; r < 4; ++r) {
      const int row = m0 + wm * 64 + mt * 16 + quad * 4 + r;
#pragma unroll
      for (int nt = 0; nt < 2; ++nt) {
        const int col = n0 + wn * 32 + nt * 16 + c16;
        Cv[(size_t)col * TS + row] = f2bf(acc[2][mt][nt][r]);
      }
    }
  }
}

// ---------------- out-proj GEMM: 128x128 tile, FULL K, fused residual epilogue --------
// (round-12 verified; frozen as control)
__global__ __launch_bounds__(512, 2) void gemm_out(
    const u16t* __restrict__ A, const u16t* __restrict__ B0,
    const float* __restrict__ xres, const int* __restrict__ am,
    float* __restrict__ out) {
  __shared__ u16t Ab[2][128 * 64];   // 32 KB
  __shared__ u16t Bb[2][128 * 64];   // 32 KB
  const int tid  = threadIdx.x;
  const int wave = tid >> 6;
  const int lane = tid & 63;
  const int quad = lane >> 4;
  const int c16  = lane & 15;
  const int h7   = c16 & 7;
  const int wm   = wave >> 2;        // 0..1  (row half: 64 rows)
  const int wn   = wave & 3;         // 0..3  (col quarter: 32 cols)
  const int bid  = blockIdx.x;
  const int wgid = (bid & 7) * 32 + (bid >> 3);   // XCD swizzle, bijective at 256
  const int m0   = (wgid & 15) * 128;
  const int n0   = (wgid >> 4) * 128;

  const int srow = lane >> 3;
  const int sg   = (lane & 7) ^ srow;
  auto stage = [&](int d, int k0) {
    const size_t koff = (size_t)k0 + sg * 8;
#pragma unroll
    for (int c = 0; c < 2; ++c) {
      const int rb = wave * 16 + c * 8;
      async_copy16(A  + (size_t)(m0 + rb + srow) * DM + koff, &Ab[d][rb * 64]);
      async_copy16(B0 + (size_t)(n0 + rb + srow) * DM + koff, &Bb[d][rb * 64]);
    }
  };

  const f32x4 fzero = {0.f, 0.f, 0.f, 0.f};
  f32x4 acc[4][2];
#pragma unroll
  for (int i = 0; i < 4; ++i)
#pragma unroll
    for (int j = 0; j < 2; ++j) acc[i][j] = fzero;

  stage(0, 0);
  asm volatile("s_waitcnt vmcnt(0)" ::: "memory");
  __builtin_amdgcn_s_barrier();

  for (int kt = 0; kt < DM / 64; ++kt) {
    const int cur = kt & 1;
    if (kt + 1 < DM / 64) stage(cur ^ 1, (kt + 1) * 64);
    const u16t* Abuf = Ab[cur];
    const u16t* Bbuf = Bb[cur];
    __builtin_amdgcn_s_setprio(1);
#pragma unroll
    for (int ks = 0; ks < 2; ++ks) {
      const int gsw = ((ks * 4 + quad) ^ h7) * 8;
      short8 af[4], bfr[2];
#pragma unroll
      for (int i = 0; i < 4; ++i)
        af[i] = *(const short8*)(Abuf + (wm * 64 + i * 16 + c16) * 64 + gsw);
#pragma unroll
      for (int nt = 0; nt < 2; ++nt)
        bfr[nt] = *(const short8*)(Bbuf + (wn * 32 + nt * 16 + c16) * 64 + gsw);
#pragma unroll
      for (int i = 0; i < 4; ++i)
#pragma unroll
        for (int nt = 0; nt < 2; ++nt)
          acc[i][nt] =
              __builtin_amdgcn_mfma_f32_16x16x32_bf16(af[i], bfr[nt], acc[i][nt], 0, 0, 0);
    }
    __builtin_amdgcn_s_setprio(0);
    asm volatile("s_waitcnt vmcnt(0)" ::: "memory");
    __builtin_amdgcn_s_barrier();
  }

  // fused residual + row-mask epilogue, fp32 store direct to output
#pragma unroll
  for (int mt = 0; mt < 4; ++mt) {
#pragma unroll
    for (int r = 0; r < 4; ++r) {
      const int row = m0 + wm * 64 + mt * 16 + quad * 4 + r;
      const float mk = (am[row] != 0) ? 1.f : 0.f;
      const size_t base = (size_t)row * DM;
#pragma unroll
      for (int nt = 0; nt < 2; ++nt) {
        const int col = n0 + wn * 32 + nt * 16 + c16;
        out[base + col] = xres[base + col] + mk * acc[mt][nt][r];
      }
    }
  }
}

// ---------------- Flash attention (causal), SWAPPED QK^T, in-register softmax ----------
// Round-12 rework (T12): compute S^T = mfma(K, Q) so each lane holds all 32 S values of
// ONE q-row (q = q0+c16; keys = quad*4+r+16ns). Softmax: in-lane reduce + 2 shfl_xor
// (vs 8 DPP ladders); scalar m/l/alpha (vs 4-wide). P -> bf16 pairs via
// v_cvt_pk_bf16_f32, 16 packed ds_write_b32 into an XOR-swizzled per-wave u32 block,
// read back as 4 ds_read_b128 B-fragments. PV computes out^T = mfma(Vt-rows, P) —
// Vt is already [d][key] so K/V staging + all LDS addressing identical to r5 verified.
// Epilogue: once-per-block LDS transpose -> coalesced 16B O stores.
__global__ __launch_bounds__(256) void attn_kernel(const u16t* __restrict__ Q,
                                                   const u16t* __restrict__ K,
                                                   const u16t* __restrict__ Vt,
                                                   const int* __restrict__ am,
                                                   u16t* __restrict__ O) {
  __shared__ u16t Klds[128 * 128];   // [key][d], swizzled granules, 32 KB
  __shared__ u16t Vlds[128 * 128];   // [d][key], swizzled granules, 32 KB
  __shared__ u16t Plds[4][2048];     // per-wave P (packed u32) / O-transpose, 16 KB
  const int wave = threadIdx.x >> 6;
  const int lane = threadIdx.x & 63;
  const int x    = blockIdx.x;
  const int half = x >> 8;                  // 0: qt 31..16, 1: qt 0..15
  const int idx  = x & 255;
  const int head = idx & (NH - 1);
  const int grp  = idx >> 4;                // 0..15
  const int qt   = half ? grp : (TS / 64 - 1 - grp);
  const int q0   = qt * 64 + wave * 16;
  const int quad = lane >> 4;
  const int c16  = lane & 15;
  const u16t* Qh  = Q + head * DH;
  const u16t* Kh  = K + head * DH;
  const u16t* Vth = Vt + (size_t)head * DH * TS;
  u16t* Pw = Plds[wave];
  uint32_t* Pw32 = (uint32_t*)Pw;
  const int pswz = (c16 & 7) << 2;          // u32-level XOR (bits 2-4), b128-safe

  const int row_s = (lane >> 4);    // 0..3 row within chunk
  const int g_s   = (lane & 15);    // granule slot

  short8 qf[4];
#pragma unroll
  for (int dc = 0; dc < 4; ++dc)
    qf[dc] = *(const short8*)(Qh + (size_t)(q0 + c16) * DM + dc * 32 + quad * 8);

  const f32x4 fzero = {0.f, 0.f, 0.f, 0.f};
  float m_run = -1e30f, l_run = 0.f;
  f32x4 o_acc[8];                   // out^T[d = mt*16+quad*4+r][q = c16]
#pragma unroll
  for (int mt = 0; mt < 8; ++mt) o_acc[mt] = fzero;

  const float scale = 0.08838834764831845f;  // 1/sqrt(128)
  const int ntiles = (qt * 64 + 191) >> 7;   // 128-wide tiles covering keys 0..q0+63
  const int qrow = q0 + c16;

  for (int kt = 0; kt < ntiles; ++kt) {
    const int k0 = kt * 128;
    __syncthreads();
#pragma unroll
    for (int c = 0; c < 8; ++c) {
      const int ch = wave * 8 + c;
      const int r  = 4 * ch + row_s;           // 0..127
      const int g  = g_s ^ (r & 15);
      async_copy16(Kh + (size_t)(k0 + r) * DM + g * 8, Klds + ch * 512);
      async_copy16(Vth + (size_t)r * TS + k0 + g * 8, Vlds + ch * 512);
    }
    __syncthreads();

    // S^T = K . Q^T : lane holds S^T[key = k0+ns*16+quad*4+r][q = qrow]
    f32x4 s[8];
#pragma unroll
    for (int ns = 0; ns < 8; ++ns) {
      f32x4 sa = fzero;
      const int rr = ns * 16 + c16;
#pragma unroll
      for (int dc = 0; dc < 4; ++dc) {
        short8 kf = *(const short8*)(Klds + rr * 128 + (((dc * 4 + quad) ^ c16) * 8));
        sa = __builtin_amdgcn_mfma_f32_16x16x32_bf16(kf, qf[dc], sa, 0, 0, 0);
      }
      s[ns] = sa;
    }

    // mask + in-lane max over this q-row's 32 keys
    float pv[8][4];
    float tmax = -1e30f;
#pragma unroll
    for (int ns = 0; ns < 8; ++ns) {
      const i32x4 a4 = *(const i32x4*)(am + k0 + ns * 16 + quad * 4);
#pragma unroll
      for (int r = 0; r < 4; ++r) {
        const int key = k0 + ns * 16 + quad * 4 + r;
        float v = s[ns][r] * scale;
        if (key > qrow || a4[r] == 0) v = -1e30f;
        pv[ns][r] = v;
        tmax = fmaxf(tmax, v);
      }
    }
    // full-row reduce across the 4 quads holding this q-row
    tmax = fmaxf(tmax, __shfl_xor(tmax, 16, 64));
    tmax = fmaxf(tmax, __shfl_xor(tmax, 32, 64));
    const float mn = fmaxf(m_run, tmax);
    const float alpha = __expf(m_run - mn);
    m_run = mn;
    float rs = 0.f;
#pragma unroll
    for (int ns = 0; ns < 8; ++ns)
#pragma unroll
      for (int r = 0; r < 4; ++r) {
        const float e = __expf(pv[ns][r] - mn);
        pv[ns][r] = e;
        rs += e;
      }
    rs += __shfl_xor(rs, 16, 64);
    rs += __shfl_xor(rs, 32, 64);
    l_run = l_run * alpha + rs;

    // pack P to bf16 pairs; store as [q=c16 row][key-pair], XOR-swizzled u32 layout.
    // logical u32 L = ns*8 + quad*2 + i covers keys ns*16+quad*4+2i, +2i+1.
#pragma unroll
    for (int ns = 0; ns < 8; ++ns)
#pragma unroll
      for (int i = 0; i < 2; ++i) {
        uint32_t pk;
        asm("v_cvt_pk_bf16_f32 %0, %1, %2"
            : "=v"(pk) : "v"(pv[ns][2 * i]), "v"(pv[ns][2 * i + 1]));
        Pw32[c16 * 64 + ((ns * 8 + quad * 2 + i) ^ pswz)] = pk;
      }
    asm volatile("s_waitcnt lgkmcnt(0)" ::: "memory");
    // B-fragments: pa[kb] = P[q=c16][keys kb*32 + quad*8 + 0..7]
    short8 pa[4];
#pragma unroll
    for (int kb = 0; kb < 4; ++kb)
      pa[kb] = *(const short8*)(Pw32 + c16 * 64 + ((kb * 16 + quad * 4) ^ pswz));

    // rescale + PV: o_acc[mt] = mfma(A = Vt[d-rows], B = pa)
#pragma unroll
    for (int mt = 0; mt < 8; ++mt)
#pragma unroll
      for (int r = 0; r < 4; ++r) o_acc[mt][r] *= alpha;
#pragma unroll
    for (int mt = 0; mt < 8; ++mt) {
      const int rrv = mt * 16 + c16;           // d-row
#pragma unroll
      for (int kb = 0; kb < 4; ++kb) {
        short8 vf = *(const short8*)(Vlds + rrv * 128 + (((kb * 4 + quad) ^ c16) * 8));
        o_acc[mt] = __builtin_amdgcn_mfma_f32_16x16x32_bf16(vf, pa[kb], o_acc[mt], 0, 0, 0);
      }
    }
  }

  // epilogue: normalize, transpose via per-wave LDS, coalesced 16B stores
  const float inv = 1.0f / fmaxf(l_run, 1e-20f);
#pragma unroll
  for (int mt = 0; mt < 8; ++mt)
#pragma unroll
    for (int r = 0; r < 4; ++r) {
      const int d = mt * 16 + quad * 4 + r;
      Pw[c16 * 128 + d] = f2bf(o_acc[mt][r] * inv);
    }
  asm volatile("s_waitcnt lgkmcnt(0)" ::: "memory");
#pragma unroll
  for (int p = 0; p < 4; ++p) {
    const int row = p * 4 + quad;              // q-local 0..15
    short8 v = *(const short8*)(Pw + row * 128 + c16 * 8);
    *(short8*)(O + (size_t)(q0 + row) * DM + head * DH + c16 * 8) = v;
  }
}

extern "C" void kernel_launch(void* const* d_in, const int* in_sizes, int n_in,
                              void* d_out, int out_size, void* d_ws, size_t ws_size,
                              hipStream_t stream) {
  const float* x    = (const float*)d_in[0];
  const float* cosb = (const float*)d_in[1];
  const float* sinb = (const float*)d_in[2];
  const int*   am   = (const int*)d_in[3];
  const float* lnw  = (const float*)d_in[4];
  const float* Wq   = (const float*)d_in[5];
  const float* Wk   = (const float*)d_in[6];
  const float* Wv   = (const float*)d_in[7];
  const float* Wo   = (const float*)d_in[8];
  float* out = (float*)d_out;

  u16t* h    = (u16t*)d_ws;                 // (T, D) bf16   [0, 8 MB)
  u16t* Q    = h + (size_t)TS * DM;         //               [8, 16)
  u16t* K    = Q + (size_t)TS * DM;         //               [16, 24)
  u16t* Vt   = K + (size_t)TS * DM;         //               [24, 32)
  u16t* attn = Vt + (size_t)TS * DM;        //               [32, 40)
  u16t* Wb   = attn + (size_t)TS * DM;      // 4 x (D, D)    [40, 72)
  u16t* Wqb = Wb;
  u16t* Wkb = Wb + (size_t)DM * DM;
  u16t* Wvb = Wb + 2 * (size_t)DM * DM;
  u16t* Wob = Wb + 3 * (size_t)DM * DM;

  cast_rms_kernel<<<16384 + TS, 256, 0, stream>>>(Wq, Wk, Wv, Wo, Wb, x, lnw, h);
  // fused QKV: 16x16 tiles = 256 blocks (1/CU), all 3 matrices per block
  gemm_qkv<<<256, 512, 0, stream>>>(h, Wqb, Wkb, Wvb, Q, K, Vt, cosb, sinb);
  attn_kernel<<<NH * (TS / 64), 256, 0, stream>>>(Q, K, Vt, am, attn);
  // out-proj: 128x128 tiles, full K, fused residual+mask epilogue -> out (fp32)
  gemm_out<<<256, 512, 0, stream>>>(attn, Wob, x, am, out);
}